// Round 5
// baseline (480.003 us; speedup 1.0000x reference)
//
#include <hip/hip_runtime.h>

#define N_PTS  2048
#define BATCH  64
#define NSLICE 16
#define SLICE  (N_PTS / NSLICE)   // 128 search pts per block
#define P      8                  // query points per thread (8*256 = all 2048)
#define BLK    256
#define NGROUP (2 * BATCH)        // (dir, batch) groups

static_assert(P * BLK == N_PTS, "each block covers all queries of its (b,dir)");
static_assert(SLICE <= BLK, "one staging point per thread");

// order-preserving float<->int key for signed-int atomicMin
__device__ __forceinline__ int fkey(float v) {
    int b = __float_as_int(v);
    return b >= 0 ? b : b ^ 0x7fffffff;
}
__device__ __forceinline__ float funkey(int b) {
    return __int_as_float(b >= 0 ? b : b ^ 0x7fffffff);
}

// ---------------------------------------------------------------------------
// Single fused kernel.  grid (NSLICE=16, BATCH, 2), block 256.
//
// Round-2 post-mortem: __launch_bounds__(256,8) budgeted 32 VGPR -> pm[8]
// spilled to scratch (WRITE_SIZE 8->42MB, K1 69us).  Round 1 proved this
// body fits 60 VGPR with (256,4), which is <=64 = the 8-waves/SIMD cliff,
// so the HW reaches 8 blocks/CU from the 2048-block grid without forcing
// the allocator.  Target: VALU floor 34us overlapped with 26us LDS pipe.
//
// Rounds 1-2 also showed (total - K1) ~ 67us regardless of K2 size: the
// residual is per-dispatch overhead.  So the slice-merge, jet term, and
// final write are fused here via last-block-done counters (device-scope
// atomicAdd + __threadfence; late blocks exit -- no dispatch-order
// assumption, G16-safe).  out is written by a single plain store; only a
// 516B counter memset precedes this kernel -> 2 dispatches total.
// ---------------------------------------------------------------------------
template <bool ATOMIC>
__global__ __launch_bounds__(BLK, 4) void chamfer_fused(
        const float4* __restrict__ p,
        const float4* __restrict__ q,
        float* __restrict__ wpart,   // plain: [NGROUP][NSLICE][N_PTS] f32
                                     // atomic: [NGROUP][N_PTS] int keys
        float* __restrict__ wsum,    // [NGROUP] per-group chamfer partials
        float* __restrict__ wjet,    // [BATCH] jet |d|^2 per batch
        int*   __restrict__ gc,      // [NGROUP] slice-completion counters
        int*   __restrict__ gcount,  // [1] group-completion counter
        float* __restrict__ out) {
    __shared__ float4 sQ[SLICE];        // 2 KB
    __shared__ float4 sQs4[SLICE / 4];  // 512 B: |q|^2 packed 4 per float4
    __shared__ float4 wacc[BLK / 64];
    __shared__ float  wred[BLK / 64];
    __shared__ int    sflag;

    const int tid = threadIdx.x;
    const int s   = blockIdx.x;
    const int b   = blockIdx.y;
    const int dir = blockIdx.z;
    const int g   = dir * BATCH + b;
    const float4* __restrict__ A  = dir ? q : p;   // query side
    const float4* __restrict__ Bm = dir ? p : q;   // search side
    const float4* __restrict__ Ab = A  + (size_t)b * N_PTS;
    const float4* __restrict__ Bb = Bm + (size_t)b * N_PTS + s * SLICE;

    if (tid < SLICE) {   // stage the slice, coalesced
        const float4 v = Bb[tid];
        sQ[tid] = v;
        ((float*)sQs4)[tid] = v.x * v.x + v.y * v.y + v.z * v.z + v.w * v.w;
    }
    __syncthreads();

    float4 pm[P];   // -2 * query point
    float  mn[P];
#pragma unroll
    for (int k = 0; k < P; ++k) {
        const float4 pv = Ab[tid + k * BLK];
        pm[k] = make_float4(-2.0f * pv.x, -2.0f * pv.y, -2.0f * pv.z, -2.0f * pv.w);
        mn[k] = 3.4e38f;
    }

#define CHAMFER_STEP(JJ, QS)                          \
    {                                                 \
        const float4 qv = sQ[(JJ)];                   \
        _Pragma("unroll")                             \
        for (int k = 0; k < P; ++k) {                 \
            float t = fmaf(pm[k].x, qv.x, (QS));      \
            t = fmaf(pm[k].y, qv.y, t);               \
            t = fmaf(pm[k].z, qv.z, t);               \
            t = fmaf(pm[k].w, qv.w, t);               \
            mn[k] = fminf(mn[k], t);                  \
        }                                             \
    }

    for (int j = 0; j < SLICE; j += 4) {
        const float4 qs4 = sQs4[j >> 2];
        CHAMFER_STEP(j + 0, qs4.x)
        CHAMFER_STEP(j + 1, qs4.y)
        CHAMFER_STEP(j + 2, qs4.z)
        CHAMFER_STEP(j + 3, qs4.w)
    }
#undef CHAMFER_STEP

    // epilogue: fold |p|^2 back in (pm.pm = 4 p.p, saves 8 live VGPRs)
    if (ATOMIC) {
        int* wi = (int*)wpart + (size_t)g * N_PTS;
#pragma unroll
        for (int k = 0; k < P; ++k) {
            const float4 m = pm[k];
            const float psq = 0.25f * (m.x * m.x + m.y * m.y + m.z * m.z + m.w * m.w);
            atomicMin(wi + tid + k * BLK, fkey(mn[k] + psq));
        }
    } else {
        float* wf = wpart + ((size_t)g * NSLICE + s) * N_PTS;
#pragma unroll
        for (int k = 0; k < P; ++k) {
            const float4 m = pm[k];
            const float psq = 0.25f * (m.x * m.x + m.y * m.y + m.z * m.z + m.w * m.w);
            wf[tid + k * BLK] = mn[k] + psq;
        }
    }

    // ---- fused jet term: block (dir==0, s==0) of each batch holds all 2048
    // p-queries in registers (sum p = -0.5 * sum pm); stream q from L2.
    if (dir == 0 && s == 0) {
        float ax = 0.f, ay = 0.f, az = 0.f, aw = 0.f;
#pragma unroll
        for (int k = 0; k < P; ++k) {
            ax += pm[k].x; ay += pm[k].y; az += pm[k].z; aw += pm[k].w;
        }
        ax *= -0.5f; ay *= -0.5f; az *= -0.5f; aw *= -0.5f;
        const float4* __restrict__ Qb = q + (size_t)b * N_PTS;
        for (int j = tid; j < N_PTS; j += BLK) {
            const float4 qv = Qb[j];
            ax -= qv.x; ay -= qv.y; az -= qv.z; aw -= qv.w;
        }
#pragma unroll
        for (int off = 32; off > 0; off >>= 1) {
            ax += __shfl_down(ax, off, 64);
            ay += __shfl_down(ay, off, 64);
            az += __shfl_down(az, off, 64);
            aw += __shfl_down(aw, off, 64);
        }
        if ((tid & 63) == 0) wacc[tid >> 6] = make_float4(ax, ay, az, aw);
        __syncthreads();   // block-uniform branch: safe
        if (tid == 0) {
            float dx = 0.f, dy = 0.f, dz = 0.f, dw = 0.f;
#pragma unroll
            for (int w = 0; w < BLK / 64; ++w) {
                dx += wacc[w].x; dy += wacc[w].y; dz += wacc[w].z; dw += wacc[w].w;
            }
            wjet[b] = dx * dx + dy * dy + dz * dz + dw * dw;  // plain store
        }
    }

    // ---- last-slice-block of each (dir,b) group merges the group ----
    __threadfence();                       // release partial/jet stores
    if (tid == 0) sflag = atomicAdd(&gc[g], 1);
    __syncthreads();
    if (sflag != NSLICE - 1) return;       // not last: done

    __threadfence();                       // acquire the other 15 blocks' stores
    float acc = 0.0f;
    if (ATOMIC) {
        const int* wi = (const int*)wpart + (size_t)g * N_PTS;
#pragma unroll
        for (int k = 0; k < P; ++k) acc += funkey(wi[tid + k * BLK]);
    } else {
        const float* wf = wpart + (size_t)g * NSLICE * N_PTS;
#pragma unroll
        for (int k = 0; k < P; ++k) {
            const int qi = tid + k * BLK;
            float m = wf[qi];
#pragma unroll
            for (int s2 = 1; s2 < NSLICE; ++s2)
                m = fminf(m, wf[(size_t)s2 * N_PTS + qi]);
            acc += m;
        }
    }
#pragma unroll
    for (int off = 32; off > 0; off >>= 1) acc += __shfl_down(acc, off, 64);
    if ((tid & 63) == 0) wred[tid >> 6] = acc;
    __syncthreads();
    if (tid == 0) {
        float sc = 0.f;
#pragma unroll
        for (int w = 0; w < BLK / 64; ++w) sc += wred[w];
        wsum[g] = sc;                      // plain store
    }

    // ---- last group-merger sums the 128 group partials + 64 jet terms ----
    __threadfence();
    if (tid == 0) sflag = atomicAdd(gcount, 1);
    __syncthreads();
    if (sflag != NGROUP - 1) return;

    __threadfence();
    float v = 0.0f;
    if (tid < NGROUP) v = wsum[tid];
    if (tid < BATCH)  v += wjet[tid];
#pragma unroll
    for (int off = 32; off > 0; off >>= 1) v += __shfl_down(v, off, 64);
    if ((tid & 63) == 0) wred[tid >> 6] = v;
    __syncthreads();
    if (tid == 0)
        out[0] = wred[0] + wred[1] + wred[2] + wred[3];  // single plain store
}

extern "C" void kernel_launch(void* const* d_in, const int* in_sizes, int n_in,
                              void* d_out, int out_size, void* d_ws, size_t ws_size,
                              hipStream_t stream) {
    const float4* p = (const float4*)d_in[0];
    const float4* q = (const float4*)d_in[1];
    float* out = (float*)d_out;
    float* ws  = (float*)d_ws;

    const size_t part_plain  = (size_t)NGROUP * NSLICE * N_PTS;  // floats (16 MB)
    const size_t part_atomic = (size_t)NGROUP * N_PTS;           // ints   (1 MB)
    const size_t tail        = NGROUP + BATCH + NGROUP + 1;      // wsum+wjet+gc+gcount

    if (ws_size >= (part_plain + tail) * sizeof(float)) {
        // deterministic plain-store path, 2 dispatches
        float* wpart  = ws;
        float* wsum   = ws + part_plain;
        float* wjet   = wsum + NGROUP;
        int*   gc     = (int*)(wjet + BATCH);
        int*   gcount = gc + NGROUP;
        hipMemsetAsync(gc, 0, (NGROUP + 1) * sizeof(int), stream);
        chamfer_fused<false><<<dim3(NSLICE, BATCH, 2), BLK, 0, stream>>>(
            p, q, wpart, wsum, wjet, gc, gcount, out);
    } else {
        // compact ~1 MB path: atomicMin on order-preserving int keys
        float* wpart  = ws;
        float* wsum   = ws + part_atomic;
        float* wjet   = wsum + NGROUP;
        int*   gc     = (int*)(wjet + BATCH);
        int*   gcount = gc + NGROUP;
        hipMemsetAsync(wpart, 0x7F, part_atomic * sizeof(int), stream);  // +3.39e38 keys
        hipMemsetAsync(gc, 0, (NGROUP + 1) * sizeof(int), stream);
        chamfer_fused<true><<<dim3(NSLICE, BATCH, 2), BLK, 0, stream>>>(
            p, q, wpart, wsum, wjet, gc, gcount, out);
    }
}

// Round 6
// 125.988 us; speedup vs baseline: 3.8099x; 3.8099x over previous
//
#include <hip/hip_runtime.h>

#define N_PTS  2048
#define BATCH  64
#define NSLICE 16
#define SLICE  (N_PTS / NSLICE)   // 128 search pts per block
#define P      8                  // query points per thread (8*256 = all 2048)
#define BLK    256
#define NGROUP (2 * BATCH)        // (dir, batch) groups
#define QSPLIT (N_PTS / BLK)      // K2 query split = 8

static_assert(P * BLK == N_PTS, "each block covers all queries of its (b,dir)");
static_assert(SLICE <= BLK, "one staging point per thread");

// order-preserving float<->int key for signed-int atomicMin (fallback path)
__device__ __forceinline__ int fkey(float v) {
    int b = __float_as_int(v);
    return b >= 0 ? b : b ^ 0x7fffffff;
}
__device__ __forceinline__ float funkey(int b) {
    return __int_as_float(b >= 0 ? b : b ^ 0x7fffffff);
}

// ---------------------------------------------------------------------------
// K1: partial chamfer mins ONLY.  grid (NSLICE=16, BATCH, 2), block 256.
//
// Round-5 post-mortem: fusing merge/jet into this kernel made the allocator
// pick 44 VGPR (< the 40+temps the loop needs live) -> hot-loop spill/remat,
// VALUBusy 97->14%, 69->450us.  Register allocation is whole-kernel max
// pressure, so NOTHING but the hot loop lives here.  Round 1 proved this
// body compiles to 60 VGPR at (256,4); 60<=64 = the 8-waves/SIMD VGPR cliff
// (m69), so the HW reaches 8 blocks/CU from the 2048-block grid on its own.
// Target: 34us VALU floor overlapped with ~26us LDS-return pipe -> ~45us.
//
// Block (0,0,0) zero-writes out[] (stream-ordered before K2's atomicAdds),
// so the plain path needs no memset dispatch: 2 dispatches total.
// ---------------------------------------------------------------------------
template <bool ATOMIC>
__global__ __launch_bounds__(BLK, 4) void chamfer_partial(
        const float4* __restrict__ p,
        const float4* __restrict__ q,
        float* __restrict__ wpart,   // plain: [NGROUP][NSLICE][N_PTS] f32
                                     // atomic: [NGROUP][N_PTS] int keys
        float* __restrict__ out) {
    __shared__ float4 sQ[SLICE];        // 2 KB
    __shared__ float4 sQs4[SLICE / 4];  // 512 B: |q|^2 packed 4 per float4

    const int tid = threadIdx.x;
    const int s   = blockIdx.x;
    const int b   = blockIdx.y;
    const int dir = blockIdx.z;
    const int g   = dir * BATCH + b;
    const float4* __restrict__ A  = dir ? q : p;   // query side
    const float4* __restrict__ Bm = dir ? p : q;   // search side
    const float4* __restrict__ Ab = A  + (size_t)b * N_PTS;
    const float4* __restrict__ Bb = Bm + (size_t)b * N_PTS + s * SLICE;

    if (s == 0 && b == 0 && dir == 0 && tid == 0) out[0] = 0.0f;

    if (tid < SLICE) {   // stage the slice, coalesced
        const float4 v = Bb[tid];
        sQ[tid] = v;
        ((float*)sQs4)[tid] = v.x * v.x + v.y * v.y + v.z * v.z + v.w * v.w;
    }
    __syncthreads();

    float4 pm[P];   // -2 * query point
    float  mn[P];
#pragma unroll
    for (int k = 0; k < P; ++k) {
        const float4 pv = Ab[tid + k * BLK];
        pm[k] = make_float4(-2.0f * pv.x, -2.0f * pv.y, -2.0f * pv.z, -2.0f * pv.w);
        mn[k] = 3.4e38f;
    }

#define CHAMFER_STEP(JJ, QS)                          \
    {                                                 \
        const float4 qv = sQ[(JJ)];                   \
        _Pragma("unroll")                             \
        for (int k = 0; k < P; ++k) {                 \
            float t = fmaf(pm[k].x, qv.x, (QS));      \
            t = fmaf(pm[k].y, qv.y, t);               \
            t = fmaf(pm[k].z, qv.z, t);               \
            t = fmaf(pm[k].w, qv.w, t);               \
            mn[k] = fminf(mn[k], t);                  \
        }                                             \
    }

    for (int j = 0; j < SLICE; j += 4) {
        const float4 qs4 = sQs4[j >> 2];
        CHAMFER_STEP(j + 0, qs4.x)
        CHAMFER_STEP(j + 1, qs4.y)
        CHAMFER_STEP(j + 2, qs4.z)
        CHAMFER_STEP(j + 3, qs4.w)
    }
#undef CHAMFER_STEP

    // epilogue: fold |p|^2 back in (pm.pm = 4 p.p, saves 8 live VGPRs)
    if (ATOMIC) {
        int* wi = (int*)wpart + (size_t)g * N_PTS;
#pragma unroll
        for (int k = 0; k < P; ++k) {
            const float4 m = pm[k];
            const float psq = 0.25f * (m.x * m.x + m.y * m.y + m.z * m.z + m.w * m.w);
            atomicMin(wi + tid + k * BLK, fkey(mn[k] + psq));
        }
    } else {
        float* wf = wpart + ((size_t)g * NSLICE + s) * N_PTS;
#pragma unroll
        for (int k = 0; k < P; ++k) {
            const float4 m = pm[k];
            const float psq = 0.25f * (m.x * m.x + m.y * m.y + m.z * m.z + m.w * m.w);
            wf[tid + k * BLK] = mn[k] + psq;
        }
    }
}

// ---------------------------------------------------------------------------
// K2: merge slice partials + jet term + final sum.  grid (QSPLIT=8, BATCH, 2),
// 256 thr, one query per thread.  ~16 MB read, ~10us.  Registers are free
// here, so the jet term (blocks dir==0, split==0) costs nothing.
// ---------------------------------------------------------------------------
template <bool ATOMIC>
__global__ __launch_bounds__(BLK) void chamfer_finish(
        const float4* __restrict__ p,
        const float4* __restrict__ q,
        const float* __restrict__ wpart,
        float* __restrict__ out) {
    __shared__ float wred[BLK / 64];
    __shared__ float4 wacc[BLK / 64];
    const int tid = threadIdx.x;
    const int qi  = blockIdx.x * BLK + tid;
    const int b   = blockIdx.y;
    const int dir = blockIdx.z;
    const int g   = dir * BATCH + b;
    const int lane = tid & 63;
    const int wid  = tid >> 6;

    float acc;
    if (ATOMIC) {
        acc = funkey(((const int*)wpart)[(size_t)g * N_PTS + qi]);
    } else {
        const float* wf = wpart + (size_t)g * NSLICE * N_PTS + qi;
        float m = wf[0];
#pragma unroll
        for (int s2 = 1; s2 < NSLICE; ++s2)
            m = fminf(m, wf[(size_t)s2 * N_PTS]);
        acc = m;
    }

#pragma unroll
    for (int off = 32; off > 0; off >>= 1) acc += __shfl_down(acc, off, 64);
    if (lane == 0) wred[wid] = acc;
    __syncthreads();
    if (tid == 0) {
        float sc = 0.f;
#pragma unroll
        for (int w = 0; w < BLK / 64; ++w) sc += wred[w];
        atomicAdd(out, sc);
    }

    // ---- jet term: blocks (split==0, dir==0), one per batch ----
    if (dir == 0 && blockIdx.x == 0) {
        const float4* __restrict__ Pb = p + (size_t)b * N_PTS;
        const float4* __restrict__ Qb = q + (size_t)b * N_PTS;
        float ax = 0.f, ay = 0.f, az = 0.f, aw = 0.f;
        for (int j = tid; j < N_PTS; j += BLK) {
            const float4 pv = Pb[j];
            const float4 qv = Qb[j];
            ax += pv.x - qv.x;
            ay += pv.y - qv.y;
            az += pv.z - qv.z;
            aw += pv.w - qv.w;
        }
#pragma unroll
        for (int off = 32; off > 0; off >>= 1) {
            ax += __shfl_down(ax, off, 64);
            ay += __shfl_down(ay, off, 64);
            az += __shfl_down(az, off, 64);
            aw += __shfl_down(aw, off, 64);
        }
        if (lane == 0) wacc[wid] = make_float4(ax, ay, az, aw);
        __syncthreads();   // block-uniform branch: safe
        if (tid == 0) {
            float dx = 0.f, dy = 0.f, dz = 0.f, dw = 0.f;
#pragma unroll
            for (int w = 0; w < BLK / 64; ++w) {
                dx += wacc[w].x; dy += wacc[w].y; dz += wacc[w].z; dw += wacc[w].w;
            }
            atomicAdd(out, dx * dx + dy * dy + dz * dz + dw * dw);
        }
    }
}

extern "C" void kernel_launch(void* const* d_in, const int* in_sizes, int n_in,
                              void* d_out, int out_size, void* d_ws, size_t ws_size,
                              hipStream_t stream) {
    const float4* p = (const float4*)d_in[0];
    const float4* q = (const float4*)d_in[1];
    float* out = (float*)d_out;
    float* ws  = (float*)d_ws;

    const size_t part_plain  = (size_t)NGROUP * NSLICE * N_PTS * sizeof(float); // 16 MB
    const size_t part_atomic = (size_t)NGROUP * N_PTS * sizeof(int);            // 1 MB

    if (ws_size >= part_plain) {
        // deterministic plain-store path: 2 dispatches, no memset
        chamfer_partial<false><<<dim3(NSLICE, BATCH, 2), BLK, 0, stream>>>(p, q, ws, out);
        chamfer_finish<false><<<dim3(QSPLIT, BATCH, 2), BLK, 0, stream>>>(p, q, ws, out);
    } else {
        // compact 1 MB fallback: atomicMin on order-preserving int keys
        hipMemsetAsync(ws, 0x7F, part_atomic, stream);  // +3.39e38 keys
        chamfer_partial<true><<<dim3(NSLICE, BATCH, 2), BLK, 0, stream>>>(p, q, ws, out);
        chamfer_finish<true><<<dim3(QSPLIT, BATCH, 2), BLK, 0, stream>>>(p, q, ws, out);
    }
}

// Round 7
// 117.199 us; speedup vs baseline: 4.0956x; 1.0750x over previous
//
#include <hip/hip_runtime.h>

#define N_PTS  2048
#define BATCH  64
#define NSLICE 16
#define SLICE  (N_PTS / NSLICE)   // 128 search pts per block
#define P      8                  // query points per thread (8*256 = all 2048)
#define BLK    256
#define NGROUP (2 * BATCH)        // (dir, batch) groups
#define QBLK4  (N_PTS / 4 / BLK)  // K2 x-split over float4 queries = 2

static_assert(P * BLK == N_PTS, "each block covers all queries of its (b,dir)");
static_assert(SLICE <= BLK, "one staging point per thread");

// order-preserving float<->int key for signed-int atomicMin (fallback path)
__device__ __forceinline__ int fkey(float v) {
    int b = __float_as_int(v);
    return b >= 0 ? b : b ^ 0x7fffffff;
}
__device__ __forceinline__ float funkey(int b) {
    return __int_as_float(b >= 0 ? b : b ^ 0x7fffffff);
}

// ---------------------------------------------------------------------------
// K1: partial chamfer mins ONLY.  grid (NSLICE=16, BATCH, 2), block 256.
//
// Round-6 post-mortem: compiler chose the MINIMUM register config (40 VGPR =
// pm[8]+mn[8] live) -> no headroom to prefetch -> each wave serializes
// ds_read-burst / lgkmcnt-wait / 320-cyc VALU.  Timing matched exactly:
// 57us = 34us VALU floor + 26us LDS pipe (5120 b128/CU x 12cyc), additive.
// Fix: explicit depth-1 prefetch rotation (next-iteration's 4 sQ + 1 sQs4
// loads issue at the top of the current iteration, #pragma unroll 1 keeps
// the structure).  The rotation forces ~20 extra live VGPRs, which is the
// point: loads now have 320 cycles of independent VALU to hide under.
// LDS padded +4 so the final prefetch reads in-bounds garbage (never used).
// Round-5 lesson: NOTHING but the hot loop lives in this kernel.
// ---------------------------------------------------------------------------
template <bool ATOMIC>
__global__ __launch_bounds__(BLK, 4) void chamfer_partial(
        const float4* __restrict__ p,
        const float4* __restrict__ q,
        float* __restrict__ wpart,   // plain: [NGROUP][NSLICE][N_PTS] f32
                                     // atomic: [NGROUP][N_PTS] int keys
        float* __restrict__ out) {
    __shared__ float4 sQ[SLICE + 4];        // +4: prefetch overrun pad
    __shared__ float4 sQs4[SLICE / 4 + 1];  // |q|^2 packed 4/float4, +1 pad

    const int tid = threadIdx.x;
    const int s   = blockIdx.x;
    const int b   = blockIdx.y;
    const int dir = blockIdx.z;
    const int g   = dir * BATCH + b;
    const float4* __restrict__ A  = dir ? q : p;   // query side
    const float4* __restrict__ Bm = dir ? p : q;   // search side
    const float4* __restrict__ Ab = A  + (size_t)b * N_PTS;
    const float4* __restrict__ Bb = Bm + (size_t)b * N_PTS + s * SLICE;

    if (s == 0 && b == 0 && dir == 0 && tid == 0) out[0] = 0.0f;

    if (tid < SLICE) {   // stage the slice, coalesced
        const float4 v = Bb[tid];
        sQ[tid] = v;
        ((float*)sQs4)[tid] = v.x * v.x + v.y * v.y + v.z * v.z + v.w * v.w;
    }
    __syncthreads();

    float4 pm[P];   // -2 * query point
    float  mn[P];
#pragma unroll
    for (int k = 0; k < P; ++k) {
        const float4 pv = Ab[tid + k * BLK];
        pm[k] = make_float4(-2.0f * pv.x, -2.0f * pv.y, -2.0f * pv.z, -2.0f * pv.w);
        mn[k] = 3.4e38f;
    }

#define CHAMFER_STEP(QV, QS)                          \
    {                                                 \
        const float4 qv = (QV);                       \
        _Pragma("unroll")                             \
        for (int k = 0; k < P; ++k) {                 \
            float t = fmaf(pm[k].x, qv.x, (QS));      \
            t = fmaf(pm[k].y, qv.y, t);               \
            t = fmaf(pm[k].z, qv.z, t);               \
            t = fmaf(pm[k].w, qv.w, t);               \
            mn[k] = fminf(mn[k], t);                  \
        }                                             \
    }

    // depth-1 software pipeline: prefetch regs for iteration j+4 are loaded
    // while iteration j's 160 VALU ops run.
    float4 nq0 = sQ[0], nq1 = sQ[1], nq2 = sQ[2], nq3 = sQ[3];
    float4 nqs = sQs4[0];
#pragma unroll 1
    for (int j = 0; j < SLICE; j += 4) {
        const float4 q0 = nq0, q1 = nq1, q2 = nq2, q3 = nq3;
        const float4 qs = nqs;
        nq0 = sQ[j + 4]; nq1 = sQ[j + 5]; nq2 = sQ[j + 6]; nq3 = sQ[j + 7];
        nqs = sQs4[(j >> 2) + 1];
        CHAMFER_STEP(q0, qs.x)
        CHAMFER_STEP(q1, qs.y)
        CHAMFER_STEP(q2, qs.z)
        CHAMFER_STEP(q3, qs.w)
    }
#undef CHAMFER_STEP

    // epilogue: fold |p|^2 back in (pm.pm = 4 p.p, saves 8 live VGPRs)
    if (ATOMIC) {
        int* wi = (int*)wpart + (size_t)g * N_PTS;
#pragma unroll
        for (int k = 0; k < P; ++k) {
            const float4 m = pm[k];
            const float psq = 0.25f * (m.x * m.x + m.y * m.y + m.z * m.z + m.w * m.w);
            atomicMin(wi + tid + k * BLK, fkey(mn[k] + psq));
        }
    } else {
        float* wf = wpart + ((size_t)g * NSLICE + s) * N_PTS;
#pragma unroll
        for (int k = 0; k < P; ++k) {
            const float4 m = pm[k];
            const float psq = 0.25f * (m.x * m.x + m.y * m.y + m.z * m.z + m.w * m.w);
            wf[tid + k * BLK] = mn[k] + psq;
        }
    }
}

// ---------------------------------------------------------------------------
// K2: merge slice partials + jet term + final sum.
// grid (QBLK4=2, BATCH, 2) = 256 blocks; each thread merges 4 consecutive
// queries across all 16 slices with float4 loads (coalesced 1KiB/wave-instr).
// Round-6 K2 (scalar, 1024 blocks) cost ~30us; this reads the same 16MB
// with 4x fewer, 4x wider instructions.
// ---------------------------------------------------------------------------
template <bool ATOMIC>
__global__ __launch_bounds__(BLK) void chamfer_finish(
        const float4* __restrict__ p,
        const float4* __restrict__ q,
        const float* __restrict__ wpart,
        float* __restrict__ out) {
    __shared__ float wred[BLK / 64];
    __shared__ float4 wacc[BLK / 64];
    const int tid  = threadIdx.x;
    const int qi4  = blockIdx.x * BLK + tid;   // float4-granular query index
    const int b    = blockIdx.y;
    const int dir  = blockIdx.z;
    const int g    = dir * BATCH + b;
    const int lane = tid & 63;
    const int wid  = tid >> 6;

    float acc;
    if (ATOMIC) {
        const int4 v = ((const int4*)wpart)[(size_t)g * (N_PTS / 4) + qi4];
        acc = funkey(v.x) + funkey(v.y) + funkey(v.z) + funkey(v.w);
    } else {
        const float4* wf = (const float4*)wpart + (size_t)g * NSLICE * (N_PTS / 4);
        float4 m = wf[qi4];
#pragma unroll
        for (int s2 = 1; s2 < NSLICE; ++s2) {
            const float4 v = wf[(size_t)s2 * (N_PTS / 4) + qi4];
            m.x = fminf(m.x, v.x); m.y = fminf(m.y, v.y);
            m.z = fminf(m.z, v.z); m.w = fminf(m.w, v.w);
        }
        acc = (m.x + m.y) + (m.z + m.w);
    }

#pragma unroll
    for (int off = 32; off > 0; off >>= 1) acc += __shfl_down(acc, off, 64);
    if (lane == 0) wred[wid] = acc;
    __syncthreads();
    if (tid == 0) {
        float sc = 0.f;
#pragma unroll
        for (int w = 0; w < BLK / 64; ++w) sc += wred[w];
        atomicAdd(out, sc);
    }

    // ---- jet term: blocks (x==0, dir==0), one per batch ----
    if (dir == 0 && blockIdx.x == 0) {
        const float4* __restrict__ Pb = p + (size_t)b * N_PTS;
        const float4* __restrict__ Qb = q + (size_t)b * N_PTS;
        float ax = 0.f, ay = 0.f, az = 0.f, aw = 0.f;
        for (int j = tid; j < N_PTS; j += BLK) {
            const float4 pv = Pb[j];
            const float4 qv = Qb[j];
            ax += pv.x - qv.x;
            ay += pv.y - qv.y;
            az += pv.z - qv.z;
            aw += pv.w - qv.w;
        }
#pragma unroll
        for (int off = 32; off > 0; off >>= 1) {
            ax += __shfl_down(ax, off, 64);
            ay += __shfl_down(ay, off, 64);
            az += __shfl_down(az, off, 64);
            aw += __shfl_down(aw, off, 64);
        }
        if (lane == 0) wacc[wid] = make_float4(ax, ay, az, aw);
        __syncthreads();   // block-uniform branch: safe
        if (tid == 0) {
            float dx = 0.f, dy = 0.f, dz = 0.f, dw = 0.f;
#pragma unroll
            for (int w = 0; w < BLK / 64; ++w) {
                dx += wacc[w].x; dy += wacc[w].y; dz += wacc[w].z; dw += wacc[w].w;
            }
            atomicAdd(out, dx * dx + dy * dy + dz * dz + dw * dw);
        }
    }
}

extern "C" void kernel_launch(void* const* d_in, const int* in_sizes, int n_in,
                              void* d_out, int out_size, void* d_ws, size_t ws_size,
                              hipStream_t stream) {
    const float4* p = (const float4*)d_in[0];
    const float4* q = (const float4*)d_in[1];
    float* out = (float*)d_out;
    float* ws  = (float*)d_ws;

    const size_t part_plain  = (size_t)NGROUP * NSLICE * N_PTS * sizeof(float); // 16 MB
    const size_t part_atomic = (size_t)NGROUP * N_PTS * sizeof(int);            // 1 MB

    if (ws_size >= part_plain) {
        // deterministic plain-store path: 2 dispatches, no memset
        chamfer_partial<false><<<dim3(NSLICE, BATCH, 2), BLK, 0, stream>>>(p, q, ws, out);
        chamfer_finish<false><<<dim3(QBLK4, BATCH, 2), BLK, 0, stream>>>(p, q, ws, out);
    } else {
        // compact 1 MB fallback: atomicMin on order-preserving int keys
        hipMemsetAsync(ws, 0x7F, part_atomic, stream);  // +3.39e38 keys
        chamfer_partial<true><<<dim3(NSLICE, BATCH, 2), BLK, 0, stream>>>(p, q, ws, out);
        chamfer_finish<true><<<dim3(QBLK4, BATCH, 2), BLK, 0, stream>>>(p, q, ws, out);
    }
}